// Round 10
// baseline (261.799 us; speedup 1.0000x reference)
//
#include <hip/hip_runtime.h>
#include <stdint.h>

#define BB 8
#define CC 512
#define NN 2304
#define NT16 (NN / 16)  // 144
#define NT32 (NN / 32)  // 72
#define CT32 (CC / 32)  // 16
#define NYB 48          // k_fc y-blocks (stats partials)

typedef float f32x4 __attribute__((ext_vector_type(4)));
typedef short s16x8 __attribute__((ext_vector_type(8)));

__device__ __forceinline__ unsigned short f2bf(float f) {
  union { float f; uint32_t u; } v; v.f = f;
  uint32_t u = v.u;
  return (unsigned short)((u + 0x7FFFu + ((u >> 16) & 1u)) >> 16);
}
__device__ __forceinline__ float bf2f(unsigned short b) {
  union { uint32_t u; float f; } v; v.u = ((uint32_t)b) << 16;
  return v.f;
}
__device__ __forceinline__ uint32_t cvtpk(float lo, float hi) {
  uint32_t r;
  asm("v_cvt_pk_bf16_f32 %0, %1, %2" : "=v"(r) : "v"(lo), "v"(hi));
  return r;
}

// Tiled layout everywhere: buf[row/16][k/32][16][32], 1KB tiles matching the MFMA
// fragment (lane l15 = row, 8*lq = k-offset) -> fragment load = one contiguous
// 1KB wave transaction (R4 win). R8: k_vt fused into k_qkv; k_fc emits bf16.
// R9 lesson: i-tile 32 LOWERED per-block arithmetic intensity -> regressed; keep 48.
// R10: 128-j double-phase in k_attn -> ONE barrier per 128 j (18 barriers vs 36).

// ---------------- prep: bf16 [Wq|Wk|Wv] rows -> wcat_t tiles; Wfc -> wfc_t tiles ----------------
__global__ void k_prep_w(const float* __restrict__ Wq, const float* __restrict__ Wk,
                         const float* __restrict__ Wv, const float* __restrict__ Wfc,
                         unsigned short* __restrict__ wcat_t, unsigned short* __restrict__ wfc_t) {
  int idx = blockIdx.x * 256 + threadIdx.x;
  const int tot_cat = 640 * 512;
  if (idx < tot_cat) {
    int tile = idx >> 9, inner = idx & 511;
    int j = (tile >> 4) * 16 + (inner >> 5);
    int k = (tile & 15) * 32 + (inner & 31);
    float v = (j < 64) ? Wq[j * 512 + k] : ((j < 128) ? Wk[(j - 64) * 512 + k] : Wv[(j - 128) * 512 + k]);
    wcat_t[idx] = f2bf(v);
  } else if (idx < tot_cat + 512 * 512) {
    int i2 = idx - tot_cat;
    int tile = i2 >> 9, inner = i2 & 511;
    int j = (tile >> 4) * 16 + (inner >> 5);
    int k = (tile & 15) * 32 + (inner & 31);
    wfc_t[i2] = f2bf(Wfc[j * 512 + k]);
  }
}

// ---------------- px_t[(b*NN+n)/16][c/32][16][32] = bf16(x[b][c][n]) ----------------
__global__ void k_px(const float* __restrict__ x, unsigned short* __restrict__ px_t) {
  __shared__ float t[32][33];
  int b = blockIdx.x;
  int nb = blockIdx.y * 32;
  int cb0 = blockIdx.z * 128;
  int lane = threadIdx.x & 31;
  int row = threadIdx.x >> 5;  // 0..7
  const float* xb = x + (size_t)b * CC * NN;
  int rbase = (b * NN + nb) >> 4;
  for (int z = 0; z < 4; z++) {
    int cb = cb0 + z * 32;
    for (int rr = 0; rr < 4; rr++) {
      int c = cb + row + 8 * rr;
      t[row + 8 * rr][lane] = xb[(size_t)c * NN + nb + lane];
    }
    __syncthreads();
    int ct = cb >> 5;
    for (int rr = 0; rr < 4; rr++) {
      int nl = row + 8 * rr;  // 0..31
      size_t off = ((size_t)(rbase + (nl >> 4)) * CT32 + ct) * 512 + (nl & 15) * 32 + lane;
      px_t[off] = f2bf(t[lane][nl]);
    }
    __syncthreads();
  }
}

// ---------------- QKV GEMM, z=3: z0 -> q_t+k_t (tanh/align), z1,2 -> vt_t DIRECT ----------------
__global__ __launch_bounds__(256, 2) void k_qkv(const unsigned short* __restrict__ px_t,
                                                const unsigned short* __restrict__ wcat_t,
                                                const float* __restrict__ align_w,
                                                unsigned short* __restrict__ q_t,
                                                unsigned short* __restrict__ k_t,
                                                unsigned short* __restrict__ vt_t) {
  int bid = blockIdx.x;
  int b = bid & 7;
  int t = bid >> 3;        // 0..107
  int z = t % 3;
  int nb = (t / 3) * 64;
  int tid = threadIdx.x;
  int w = tid >> 6, l = tid & 63, l15 = l & 15, lq = l >> 4;
  int loff = l15 * 32 + 8 * lq;
  int rA = (b * NN + nb) >> 4;
  int nfmax = (z == 0) ? 2 : 4;
  int rowB0 = (z == 0) ? 2 * w : 8 + (z - 1) * 16 + 4 * w;  // wcat_t row-tile base
  f32x4 acc[4][4];
  for (int mf = 0; mf < 4; mf++) for (int nf = 0; nf < 4; nf++) acc[mf][nf] = (f32x4){0.f, 0.f, 0.f, 0.f};
  for (int kk = 0; kk < 16; kk++) {
    s16x8 a[4], bbf[4];
    for (int mf = 0; mf < 4; mf++)
      a[mf] = *(const s16x8*)(px_t + ((size_t)(rA + mf) * CT32 + kk) * 512 + loff);
    for (int nf = 0; nf < 4; nf++)
      if (nf < nfmax)
        bbf[nf] = *(const s16x8*)(wcat_t + ((size_t)(rowB0 + nf) * CT32 + kk) * 512 + loff);
    for (int mf = 0; mf < 4; mf++)
      for (int nf = 0; nf < 4; nf++)
        if (nf < nfmax)
          acc[mf][nf] = __builtin_amdgcn_mfma_f32_16x16x32_bf16(a[mf], bbf[nf], acc[mf][nf], 0, 0, 0);
  }
  if (z == 0) {
    // j = 32w + 16nf + l15; w<2 -> q (j<64), w>=2 -> k
    for (int mf = 0; mf < 4; mf++)
      for (int nf = 0; nf < 2; nf++)
        for (int r = 0; r < 4; r++) {
          int j = 32 * w + 16 * nf + l15;
          int nl = 4 * lq + r;
          float v = tanhf(acc[mf][nf][r]);
          if (w < 2) {
            v *= align_w[j];
            q_t[((size_t)(rA + mf) * 2 + w) * 512 + nl * 32 + (j & 31)] = f2bf(v);
          } else {
            k_t[((size_t)(rA + mf) * 2 + (w - 2)) * 512 + nl * 32 + (j & 31)] = f2bf(v);
          }
        }
  } else {
    // c = (z-1)*256 + 64w + 16nf + l15 ; n = nb + 16mf + 4lq + r (r=0..3 consecutive)
    unsigned short* vtb = vt_t + (size_t)b * (CC / 16) * NT32 * 512;
    for (int mf = 0; mf < 4; mf++)
      for (int nf = 0; nf < 4; nf++) {
        int c = (z - 1) * 256 + 64 * w + 16 * nf + l15;
        uint2 pp;
        pp.x = cvtpk(acc[mf][nf][0], acc[mf][nf][1]);
        pp.y = cvtpk(acc[mf][nf][2], acc[mf][nf][3]);
        int nlo = 16 * (mf & 1) + 4 * lq;
        size_t off = ((size_t)(c >> 4) * NT32 + (nb >> 5) + (mf >> 1)) * 512 + (c & 15) * 32 + nlo;
        *(uint2*)(vtb + off) = pp;
      }
  }
}

// ---------------- fused attention, i-tile 48, c-split x2, 128-j phases ----------------
// grid 768 = 8b x 2ch x 24ib -> exactly 3 blocks/CU (R8 geometry, the 83us config).
// R10: each phase covers 128 j (two 64-j score halves into one 12KB e-buffer) with
// ONE raw s_barrier + lgkmcnt(0) -> 18 barriers instead of 36, 60 MFMA per barrier.
// K loads issued before V (in-order vmcnt: scores wait K only). e_s parity dbuf
// (iter t reads buf[t&1] after barrier; iter t+1 writes buf[(t+1)&1]) -> no
// trailing barrier. Swapped QK^T (lane-local consecutive j) + cvt_pk packing.
__global__ __launch_bounds__(256, 3) void k_attn(const unsigned short* __restrict__ q_t,
                                                 const unsigned short* __restrict__ k_t,
                                                 const unsigned short* __restrict__ vt_t,
                                                 unsigned short* __restrict__ px_t /* content in-place */) {
  __shared__ __align__(16) unsigned short e_s[2][48 * 128];
  __shared__ float rs_s[4][48];
  int bid = blockIdx.x;
  int b = bid & 7;           // XCD pin
  int ch = ((bid >> 3) & 1) * 256;
  int ib = (bid >> 4) * 48;
  int tid = threadIdx.x;
  int w = tid >> 6, l = tid & 63, l15 = l & 15, lq = l >> 4;
  int c0 = ch + 64 * w;
  int loff = l15 * 32 + 8 * lq;
  int rQ = (b * NN + ib) >> 4;
  int ktb = b * NT16;
  const unsigned short* vb = vt_t + (size_t)b * (CC / 16) * NT32 * 512;

  s16x8 qa[3][2];
  for (int mf = 0; mf < 3; mf++)
    for (int ks = 0; ks < 2; ks++)
      qa[mf][ks] = *(const s16x8*)(q_t + ((size_t)(rQ + mf) * 2 + ks) * 512 + loff);

  f32x4 acc[3][4];
  for (int mf = 0; mf < 3; mf++) for (int nf = 0; nf < 4; nf++) acc[mf][nf] = (f32x4){0.f, 0.f, 0.f, 0.f};
  float rs[3] = {0.f, 0.f, 0.f};

  const int NP = NN / 128;  // 18 phases
  for (int p = 0; p < NP; p++) {
    char* ebuf = (char*)e_s[p & 1];
    // ---- K for both halves first (scores drain only these; V stays in flight) ----
    s16x8 kf[2][2];
    for (int h = 0; h < 2; h++)
      for (int kp = 0; kp < 2; kp++)
        kf[h][kp] = *(const s16x8*)(k_t + ((size_t)(ktb + (2 * p + h) * 4 + w) * 2 + kp) * 512 + loff);
    // ---- V for both halves: 16 coalesced 1KB tile loads ----
    s16x8 vf[2][2][4];
    for (int h = 0; h < 2; h++)
      for (int kp = 0; kp < 2; kp++)
        for (int nf = 0; nf < 4; nf++)
          vf[h][kp][nf] = *(const s16x8*)(vb + ((size_t)((c0 >> 4) + nf) * NT32 + 4 * p + 2 * h + kp) * 512 + loff);
    // ---- scores per half: lane (l15,lq) reg r = S[i=16mf+l15][j=128p+64h+16w+4lq+r] ----
    for (int h = 0; h < 2; h++) {
      f32x4 sc[3];
      for (int mf = 0; mf < 3; mf++) sc[mf] = (f32x4){0.f, 0.f, 0.f, 0.f};
      __builtin_amdgcn_s_setprio(1);
      for (int kp = 0; kp < 2; kp++)
        for (int mf = 0; mf < 3; mf++)
          sc[mf] = __builtin_amdgcn_mfma_f32_16x16x32_bf16(kf[h][kp], qa[mf][kp], sc[mf], 0, 0, 0);
      __builtin_amdgcn_s_setprio(0);
      for (int mf = 0; mf < 3; mf++) {
        float e0 = __expf(sc[mf][0]), e1 = __expf(sc[mf][1]);
        float e2 = __expf(sc[mf][2]), e3 = __expf(sc[mf][3]);
        rs[mf] += (e0 + e1) + (e2 + e3);
        uint2 pp;
        pp.x = cvtpk(e0, e1);
        pp.y = cvtpk(e2, e3);
        int i_ = 16 * mf + l15;
        int byte = (i_ * 256 + (64 * h + 16 * w + 4 * lq) * 2) ^ ((i_ & 7) << 4);
        *(uint2*)(ebuf + byte) = pp;
      }
    }
    // ---- one barrier per 128 j ----
    asm volatile("s_waitcnt lgkmcnt(0)" ::: "memory");
    __builtin_amdgcn_s_barrier();
    __builtin_amdgcn_sched_barrier(0);
    // ---- PV over 4 ks slices of 32 j ----
    for (int ks = 0; ks < 4; ks++) {
      s16x8 ef[3];
      for (int mf = 0; mf < 3; mf++) {
        int i_ = 16 * mf + l15;
        int byte = (i_ * 256 + 64 * ks + 16 * lq) ^ ((i_ & 7) << 4);
        ef[mf] = *(const s16x8*)((const char*)ebuf + byte);
      }
      __builtin_amdgcn_s_setprio(1);
      for (int nf = 0; nf < 4; nf++)
        for (int mf = 0; mf < 3; mf++)
          acc[mf][nf] = __builtin_amdgcn_mfma_f32_16x16x32_bf16(ef[mf], vf[ks >> 1][ks & 1][nf], acc[mf][nf], 0, 0, 0);
      __builtin_amdgcn_s_setprio(0);
    }
    // no trailing barrier: next phase writes the other e_s buffer; this phase's
    // ds_reads drain at next phase's lgkmcnt(0) before its barrier.
  }

  // rowsum: lanes sharing l15 (same i) reduce over lq via shfl 16/32, then cross-wave
  for (int mf = 0; mf < 3; mf++) {
    float v = rs[mf];
    v += __shfl_xor(v, 16);
    v += __shfl_xor(v, 32);
    rs[mf] = v;
  }
  if (lq == 0)
    for (int mf = 0; mf < 3; mf++)
      rs_s[w][16 * mf + l15] = rs[mf];
  __syncthreads();
  float inv[3][4];
  for (int mf = 0; mf < 3; mf++)
    for (int r = 0; r < 4; r++) {
      int i = 16 * mf + 4 * lq + r;
      inv[mf][r] = 1.0f / (rs_s[0][i] + rs_s[1][i] + rs_s[2][i] + rs_s[3][i]);
    }
  // content = px + attn@v, in-place RMW on px_t (disjoint per lane/block)
  for (int mf = 0; mf < 3; mf++)
    for (int nf = 0; nf < 4; nf++)
      for (int r = 0; r < 4; r++) {
        int i = 16 * mf + 4 * lq + r;
        int bn = b * NN + ib + i;
        int c = c0 + 16 * nf + l15;
        size_t off = ((size_t)(bn >> 4) * CT32 + (c >> 5)) * 512 + (bn & 15) * 32 + (c & 31);
        px_t[off] = f2bf(bf2f(px_t[off]) + acc[mf][nf][r] * inv[mf][r]);
      }
}

// ---------------- FC + fused BN partial stats; bf16 output c16 ----------------
__global__ __launch_bounds__(256, 3) void k_fc(const unsigned short* __restrict__ px_t,
                                               const unsigned short* __restrict__ wfc_t,
                                               const float* __restrict__ bfc,
                                               unsigned short* __restrict__ c16,
                                               float2* __restrict__ partials) {
  __shared__ float pss[4][32], psq[4][32];
  int bid = blockIdx.x;
  int s_ = bid >> 3;
  int yb = (bid & 7) + 8 * (s_ % 6);
  int cb = (s_ / 6) * 32;
  int fb = yb * 384;
  int tid = threadIdx.x;
  int w = tid >> 6, l = tid & 63, l15 = l & 15, lq = l >> 4;
  int fw = fb + 96 * w;
  int loff = l15 * 32 + 8 * lq;
  f32x4 acc[2][6];
  for (int mf = 0; mf < 2; mf++) for (int nf = 0; nf < 6; nf++) acc[mf][nf] = (f32x4){0.f, 0.f, 0.f, 0.f};
  for (int kk = 0; kk < 16; kk++) {
    s16x8 a[2], bbf[6];
    for (int mf = 0; mf < 2; mf++)
      a[mf] = *(const s16x8*)(wfc_t + ((size_t)((cb >> 4) + mf) * CT32 + kk) * 512 + loff);
    for (int nf = 0; nf < 6; nf++)
      bbf[nf] = *(const s16x8*)(px_t + ((size_t)((fw >> 4) + nf) * CT32 + kk) * 512 + loff);
    for (int mf = 0; mf < 2; mf++)
      for (int nf = 0; nf < 6; nf++)
        acc[mf][nf] = __builtin_amdgcn_mfma_f32_16x16x32_bf16(a[mf], bbf[nf], acc[mf][nf], 0, 0, 0);
  }
  float s8[2][4], q8[2][4];
  for (int mf = 0; mf < 2; mf++)
    for (int r = 0; r < 4; r++) {
      int c2 = cb + 16 * mf + 4 * lq + r;
      float bias = bfc[c2];
      float s = 0.f, q = 0.f;
      for (int nf = 0; nf < 6; nf++) {
        float v = acc[mf][nf][r] + bias;
        int flat = fw + 16 * nf + l15;
        int b2 = flat / NN;
        int n = flat - b2 * NN;
        c16[((size_t)b2 * CC + c2) * NN + n] = f2bf(v);
        s += v; q += v * v;
      }
      s8[mf][r] = s; q8[mf][r] = q;
    }
  for (int mf = 0; mf < 2; mf++)
    for (int r = 0; r < 4; r++) {
      float s = s8[mf][r], q = q8[mf][r];
      s += __shfl_xor(s, 1); q += __shfl_xor(q, 1);
      s += __shfl_xor(s, 2); q += __shfl_xor(q, 2);
      s += __shfl_xor(s, 4); q += __shfl_xor(q, 4);
      s += __shfl_xor(s, 8); q += __shfl_xor(q, 8);
      s8[mf][r] = s; q8[mf][r] = q;
    }
  if (l15 == 0)
    for (int mf = 0; mf < 2; mf++)
      for (int r = 0; r < 4; r++) {
        int idx = 16 * mf + 4 * lq + r;
        pss[w][idx] = s8[mf][r];
        psq[w][idx] = q8[mf][r];
      }
  __syncthreads();
  if (tid < 32) {
    float s = pss[0][tid] + pss[1][tid] + pss[2][tid] + pss[3][tid];
    float q = psq[0][tid] + psq[1][tid] + psq[2][tid] + psq[3][tid];
    partials[(size_t)(cb + tid) * NYB + yb] = make_float2(s, q);
  }
}

// ---------------- BN finalize + apply + ReLU (stats reduction fused in) ----------------
__global__ void k_bn(const unsigned short* __restrict__ c16, float* __restrict__ out,
                     const float2* __restrict__ partials, const float* __restrict__ gamma,
                     const float* __restrict__ beta) {
  int idx = blockIdx.x * 256 + threadIdx.x;  // ushort8 index
  const int total = BB * CC * NN / 8;
  if (idx >= total) return;
  int c = (idx / (NN / 8)) & (CC - 1);
  float s = 0.f, q = 0.f;
#pragma unroll
  for (int i = 0; i < NYB; i++) {
    float2 p = partials[(size_t)c * NYB + i];
    s += p.x; q += p.y;
  }
  const float invn = 1.0f / (BB * NN);
  float mean = s * invn;
  float var = q * invn - mean * mean;
  float a = gamma[c] * rsqrtf(var + 1e-5f);
  float b2 = beta[c] - mean * a;
  s16x8 v = ((const s16x8*)c16)[idx];
  f32x4 o0, o1;
  for (int i = 0; i < 4; i++) o0[i] = fmaxf(0.f, bf2f((unsigned short)v[i]) * a + b2);
  for (int i = 0; i < 4; i++) o1[i] = fmaxf(0.f, bf2f((unsigned short)v[4 + i]) * a + b2);
  ((f32x4*)out)[idx * 2] = o0;
  ((f32x4*)out)[idx * 2 + 1] = o1;
}

extern "C" void kernel_launch(void* const* d_in, const int* in_sizes, int n_in,
                              void* d_out, int out_size, void* d_ws, size_t ws_size,
                              hipStream_t stream) {
  const float* x = (const float*)d_in[0];
  const float* Wq = (const float*)d_in[1];
  const float* Wk = (const float*)d_in[2];
  const float* Wv = (const float*)d_in[3];
  const float* align_w = (const float*)d_in[4];
  const float* Wfc = (const float*)d_in[5];
  const float* bfc = (const float*)d_in[6];
  const float* gamma = (const float*)d_in[7];
  const float* beta = (const float*)d_in[8];
  float* out = (float*)d_out;

  char* ws = (char*)d_ws;
  const size_t sz_px = (size_t)BB * NN * CC * 2;  // px_t / content, in-place
  const size_t sz_q = (size_t)BB * NN * 64 * 2;
  const size_t sz_vr = (size_t)BB * NN * CC * 2;
  unsigned short* px_t = (unsigned short*)(ws);
  unsigned short* q_t = (unsigned short*)(ws + sz_px);
  unsigned short* k_t = (unsigned short*)(ws + sz_px + sz_q);
  unsigned short* c16 = (unsigned short*)(ws + sz_px + 2 * sz_q);
  unsigned short* vt_t = (unsigned short*)(ws + sz_px + 2 * sz_q + sz_vr);
  unsigned short* wcat_t = (unsigned short*)(ws + sz_px + 2 * sz_q + 2 * sz_vr);
  unsigned short* wfc_t = (unsigned short*)(ws + sz_px + 2 * sz_q + 2 * sz_vr + 640 * 512 * 2);
  float2* partials = (float2*)(ws + sz_px + 2 * sz_q + 2 * sz_vr + 640 * 512 * 2 + 512 * 512 * 2);

  k_prep_w<<<(640 * 512 + 512 * 512 + 255) / 256, 256, 0, stream>>>(Wq, Wk, Wv, Wfc, wcat_t, wfc_t);
  k_px<<<dim3(BB, NN / 32, 4), 256, 0, stream>>>(x, px_t);
  k_qkv<<<864, 256, 0, stream>>>(px_t, wcat_t, align_w, q_t, k_t, vt_t);
  k_attn<<<768, 256, 0, stream>>>(q_t, k_t, vt_t, px_t);
  k_fc<<<768, 256, 0, stream>>>(px_t, wfc_t, bfc, c16, partials);
  k_bn<<<(BB * CC * NN / 8 + 255) / 256, 256, 0, stream>>>(c16, out, partials, gamma, beta);
}

// Round 11
// 172.785 us; speedup vs baseline: 1.5152x; 1.5152x over previous
//
#include <hip/hip_runtime.h>
#include <stdint.h>

#define BB 8
#define CC 512
#define NN 2304
#define NT16 (NN / 16)  // 144
#define NT32 (NN / 32)  // 72
#define CT32 (CC / 32)  // 16
#define NYB 48          // k_fc y-blocks (stats partials)

typedef float f32x4 __attribute__((ext_vector_type(4)));
typedef short s16x8 __attribute__((ext_vector_type(8)));

__device__ __forceinline__ unsigned short f2bf(float f) {
  union { float f; uint32_t u; } v; v.f = f;
  uint32_t u = v.u;
  return (unsigned short)((u + 0x7FFFu + ((u >> 16) & 1u)) >> 16);
}
__device__ __forceinline__ float bf2f(unsigned short b) {
  union { uint32_t u; float f; } v; v.u = ((uint32_t)b) << 16;
  return v.f;
}
__device__ __forceinline__ uint32_t cvtpk(float lo, float hi) {
  uint32_t r;
  asm("v_cvt_pk_bf16_f32 %0, %1, %2" : "=v"(r) : "v"(lo), "v"(hi));
  return r;
}

// Tiled layout everywhere: buf[row/16][k/32][16][32], 1KB tiles matching the MFMA
// fragment (lane l15 = row, 8*lq = k-offset) -> fragment load = one contiguous
// 1KB wave transaction (R4 win: 217->91us).
// Ledger: R6 (reorder) / R9 (4 blocks/CU, i-tile 32) / R10 (128-j phases; spilled)
// all failed to beat the R8 k_attn config -> this is the R8 kernel restored.
// R10's spill lesson: do NOT hold >8 V-fragments across the barrier at (256,3).

// ---------------- prep: bf16 [Wq|Wk|Wv] rows -> wcat_t tiles; Wfc -> wfc_t tiles ----------------
__global__ void k_prep_w(const float* __restrict__ Wq, const float* __restrict__ Wk,
                         const float* __restrict__ Wv, const float* __restrict__ Wfc,
                         unsigned short* __restrict__ wcat_t, unsigned short* __restrict__ wfc_t) {
  int idx = blockIdx.x * 256 + threadIdx.x;
  const int tot_cat = 640 * 512;
  if (idx < tot_cat) {
    int tile = idx >> 9, inner = idx & 511;
    int j = (tile >> 4) * 16 + (inner >> 5);
    int k = (tile & 15) * 32 + (inner & 31);
    float v = (j < 64) ? Wq[j * 512 + k] : ((j < 128) ? Wk[(j - 64) * 512 + k] : Wv[(j - 128) * 512 + k]);
    wcat_t[idx] = f2bf(v);
  } else if (idx < tot_cat + 512 * 512) {
    int i2 = idx - tot_cat;
    int tile = i2 >> 9, inner = i2 & 511;
    int j = (tile >> 4) * 16 + (inner >> 5);
    int k = (tile & 15) * 32 + (inner & 31);
    wfc_t[i2] = f2bf(Wfc[j * 512 + k]);
  }
}

// ---------------- px_t[(b*NN+n)/16][c/32][16][32] = bf16(x[b][c][n]) ----------------
__global__ void k_px(const float* __restrict__ x, unsigned short* __restrict__ px_t) {
  __shared__ float t[32][33];
  int b = blockIdx.x;
  int nb = blockIdx.y * 32;
  int cb0 = blockIdx.z * 128;
  int lane = threadIdx.x & 31;
  int row = threadIdx.x >> 5;  // 0..7
  const float* xb = x + (size_t)b * CC * NN;
  int rbase = (b * NN + nb) >> 4;
  for (int z = 0; z < 4; z++) {
    int cb = cb0 + z * 32;
    for (int rr = 0; rr < 4; rr++) {
      int c = cb + row + 8 * rr;
      t[row + 8 * rr][lane] = xb[(size_t)c * NN + nb + lane];
    }
    __syncthreads();
    int ct = cb >> 5;
    for (int rr = 0; rr < 4; rr++) {
      int nl = row + 8 * rr;  // 0..31
      size_t off = ((size_t)(rbase + (nl >> 4)) * CT32 + ct) * 512 + (nl & 15) * 32 + lane;
      px_t[off] = f2bf(t[lane][nl]);
    }
    __syncthreads();
  }
}

// ---------------- QKV GEMM, z=3: z0 -> q_t+k_t (tanh/align), z1,2 -> vt_t DIRECT ----------------
__global__ __launch_bounds__(256, 2) void k_qkv(const unsigned short* __restrict__ px_t,
                                                const unsigned short* __restrict__ wcat_t,
                                                const float* __restrict__ align_w,
                                                unsigned short* __restrict__ q_t,
                                                unsigned short* __restrict__ k_t,
                                                unsigned short* __restrict__ vt_t) {
  int bid = blockIdx.x;
  int b = bid & 7;
  int t = bid >> 3;        // 0..107
  int z = t % 3;
  int nb = (t / 3) * 64;
  int tid = threadIdx.x;
  int w = tid >> 6, l = tid & 63, l15 = l & 15, lq = l >> 4;
  int loff = l15 * 32 + 8 * lq;
  int rA = (b * NN + nb) >> 4;
  int nfmax = (z == 0) ? 2 : 4;
  int rowB0 = (z == 0) ? 2 * w : 8 + (z - 1) * 16 + 4 * w;  // wcat_t row-tile base
  f32x4 acc[4][4];
  for (int mf = 0; mf < 4; mf++) for (int nf = 0; nf < 4; nf++) acc[mf][nf] = (f32x4){0.f, 0.f, 0.f, 0.f};
  for (int kk = 0; kk < 16; kk++) {
    s16x8 a[4], bbf[4];
    for (int mf = 0; mf < 4; mf++)
      a[mf] = *(const s16x8*)(px_t + ((size_t)(rA + mf) * CT32 + kk) * 512 + loff);
    for (int nf = 0; nf < 4; nf++)
      if (nf < nfmax)
        bbf[nf] = *(const s16x8*)(wcat_t + ((size_t)(rowB0 + nf) * CT32 + kk) * 512 + loff);
    for (int mf = 0; mf < 4; mf++)
      for (int nf = 0; nf < 4; nf++)
        if (nf < nfmax)
          acc[mf][nf] = __builtin_amdgcn_mfma_f32_16x16x32_bf16(a[mf], bbf[nf], acc[mf][nf], 0, 0, 0);
  }
  if (z == 0) {
    // j = 32w + 16nf + l15; w<2 -> q (j<64), w>=2 -> k
    for (int mf = 0; mf < 4; mf++)
      for (int nf = 0; nf < 2; nf++)
        for (int r = 0; r < 4; r++) {
          int j = 32 * w + 16 * nf + l15;
          int nl = 4 * lq + r;
          float v = tanhf(acc[mf][nf][r]);
          if (w < 2) {
            v *= align_w[j];
            q_t[((size_t)(rA + mf) * 2 + w) * 512 + nl * 32 + (j & 31)] = f2bf(v);
          } else {
            k_t[((size_t)(rA + mf) * 2 + (w - 2)) * 512 + nl * 32 + (j & 31)] = f2bf(v);
          }
        }
  } else {
    // c = (z-1)*256 + 64w + 16nf + l15 ; n = nb + 16mf + 4lq + r (r=0..3 consecutive)
    unsigned short* vtb = vt_t + (size_t)b * (CC / 16) * NT32 * 512;
    for (int mf = 0; mf < 4; mf++)
      for (int nf = 0; nf < 4; nf++) {
        int c = (z - 1) * 256 + 64 * w + 16 * nf + l15;
        uint2 pp;
        pp.x = cvtpk(acc[mf][nf][0], acc[mf][nf][1]);
        pp.y = cvtpk(acc[mf][nf][2], acc[mf][nf][3]);
        int nlo = 16 * (mf & 1) + 4 * lq;
        size_t off = ((size_t)(c >> 4) * NT32 + (nb >> 5) + (mf >> 1)) * 512 + (c & 15) * 32 + nlo;
        *(uint2*)(vtb + off) = pp;
      }
  }
}

// ---------------- fused attention, i-tile 48, c-split x2 (R8 config: the 83us kernel) ----------------
// grid 768 = 8b x 2ch x 24ib -> exactly 3 blocks/CU, zero tail. 64-j steps,
// parity-dbuf e_s (no trailing barrier), one raw s_barrier + lgkmcnt(0) per step,
// swapped QK^T (lane-local consecutive j) + cvt_pk pack, 8 V-fragments in flight.
__global__ __launch_bounds__(256, 3) void k_attn(const unsigned short* __restrict__ q_t,
                                                 const unsigned short* __restrict__ k_t,
                                                 const unsigned short* __restrict__ vt_t,
                                                 unsigned short* __restrict__ px_t /* content in-place */) {
  __shared__ __align__(16) unsigned short e_s[2][48 * 64];
  __shared__ float rs_s[4][48];
  int bid = blockIdx.x;
  int b = bid & 7;           // XCD pin
  int ch = ((bid >> 3) & 1) * 256;
  int ib = (bid >> 4) * 48;
  int tid = threadIdx.x;
  int w = tid >> 6, l = tid & 63, l15 = l & 15, lq = l >> 4;
  int c0 = ch + 64 * w;
  int loff = l15 * 32 + 8 * lq;
  int rQ = (b * NN + ib) >> 4;
  int ktb = b * NT16;
  const unsigned short* vb = vt_t + (size_t)b * (CC / 16) * NT32 * 512;

  s16x8 qa[3][2];
  for (int mf = 0; mf < 3; mf++)
    for (int ks = 0; ks < 2; ks++)
      qa[mf][ks] = *(const s16x8*)(q_t + ((size_t)(rQ + mf) * 2 + ks) * 512 + loff);

  f32x4 acc[3][4];
  for (int mf = 0; mf < 3; mf++) for (int nf = 0; nf < 4; nf++) acc[mf][nf] = (f32x4){0.f, 0.f, 0.f, 0.f};
  float rs[3] = {0.f, 0.f, 0.f};

  s16x8 kf0[2], kf1[2];
  for (int ks = 0; ks < 2; ks++)
    kf0[ks] = *(const s16x8*)(k_t + ((size_t)(ktb + w) * 2 + ks) * 512 + loff);

  auto step = [&](int jt, char* ebuf, s16x8 (&kfu)[2], s16x8 (&kfl)[2]) {
    int jtn = (jt < NN / 64 - 1) ? jt + 1 : jt;
    s16x8 vf[2][4];
    for (int ks = 0; ks < 2; ks++)
      for (int nf = 0; nf < 4; nf++)
        vf[ks][nf] = *(const s16x8*)(vb + ((size_t)((c0 >> 4) + nf) * NT32 + jt * 2 + ks) * 512 + loff);
    for (int ks = 0; ks < 2; ks++)
      kfl[ks] = *(const s16x8*)(k_t + ((size_t)(ktb + jtn * 4 + w) * 2 + ks) * 512 + loff);
    // swapped scores: lane (l15,lq) reg r = S[i = 16mf+l15][j = jb + 16w + 4lq + r]
    f32x4 sc[3];
    for (int mf = 0; mf < 3; mf++) sc[mf] = (f32x4){0.f, 0.f, 0.f, 0.f};
    __builtin_amdgcn_s_setprio(1);
    for (int ks = 0; ks < 2; ks++)
      for (int mf = 0; mf < 3; mf++)
        sc[mf] = __builtin_amdgcn_mfma_f32_16x16x32_bf16(kfu[ks], qa[mf][ks], sc[mf], 0, 0, 0);
    __builtin_amdgcn_s_setprio(0);
    for (int mf = 0; mf < 3; mf++) {
      float e0 = __expf(sc[mf][0]), e1 = __expf(sc[mf][1]);
      float e2 = __expf(sc[mf][2]), e3 = __expf(sc[mf][3]);
      rs[mf] += (e0 + e1) + (e2 + e3);
      uint2 pp;
      pp.x = cvtpk(e0, e1);
      pp.y = cvtpk(e2, e3);
      int i_ = 16 * mf + l15;
      int byte = (i_ * 128 + (16 * w + 4 * lq) * 2) ^ ((i_ & 7) << 4);
      *(uint2*)(ebuf + byte) = pp;
    }
    asm volatile("s_waitcnt lgkmcnt(0)" ::: "memory");
    __builtin_amdgcn_s_barrier();
    __builtin_amdgcn_sched_barrier(0);
    for (int ks = 0; ks < 2; ks++) {
      s16x8 ef[3];
      for (int mf = 0; mf < 3; mf++) {
        int i_ = 16 * mf + l15;
        int byte = (i_ * 128 + 64 * ks + 16 * lq) ^ ((i_ & 7) << 4);
        ef[mf] = *(const s16x8*)((const char*)ebuf + byte);
      }
      __builtin_amdgcn_s_setprio(1);
      for (int nf = 0; nf < 4; nf++)
        for (int mf = 0; mf < 3; mf++)
          acc[mf][nf] = __builtin_amdgcn_mfma_f32_16x16x32_bf16(ef[mf], vf[ks][nf], acc[mf][nf], 0, 0, 0);
      __builtin_amdgcn_s_setprio(0);
    }
  };

  for (int jt = 0; jt < NN / 64; jt += 2) {
    step(jt, (char*)e_s[0], kf0, kf1);
    step(jt + 1, (char*)e_s[1], kf1, kf0);
  }

  // rowsum: lanes sharing l15 (same i) reduce over lq via shfl 16/32, then cross-wave
  for (int mf = 0; mf < 3; mf++) {
    float v = rs[mf];
    v += __shfl_xor(v, 16);
    v += __shfl_xor(v, 32);
    rs[mf] = v;
  }
  if (lq == 0)
    for (int mf = 0; mf < 3; mf++)
      rs_s[w][16 * mf + l15] = rs[mf];
  __syncthreads();
  float inv[3][4];
  for (int mf = 0; mf < 3; mf++)
    for (int r = 0; r < 4; r++) {
      int i = 16 * mf + 4 * lq + r;
      inv[mf][r] = 1.0f / (rs_s[0][i] + rs_s[1][i] + rs_s[2][i] + rs_s[3][i]);
    }
  // content = px + attn@v, in-place RMW on px_t (disjoint per lane/block)
  for (int mf = 0; mf < 3; mf++)
    for (int nf = 0; nf < 4; nf++)
      for (int r = 0; r < 4; r++) {
        int i = 16 * mf + 4 * lq + r;
        int bn = b * NN + ib + i;
        int c = c0 + 16 * nf + l15;
        size_t off = ((size_t)(bn >> 4) * CT32 + (c >> 5)) * 512 + (bn & 15) * 32 + (c & 31);
        px_t[off] = f2bf(bf2f(px_t[off]) + acc[mf][nf][r] * inv[mf][r]);
      }
}

// ---------------- FC + fused BN partial stats; bf16 output c16 ----------------
__global__ __launch_bounds__(256, 3) void k_fc(const unsigned short* __restrict__ px_t,
                                               const unsigned short* __restrict__ wfc_t,
                                               const float* __restrict__ bfc,
                                               unsigned short* __restrict__ c16,
                                               float2* __restrict__ partials) {
  __shared__ float pss[4][32], psq[4][32];
  int bid = blockIdx.x;
  int s_ = bid >> 3;
  int yb = (bid & 7) + 8 * (s_ % 6);
  int cb = (s_ / 6) * 32;
  int fb = yb * 384;
  int tid = threadIdx.x;
  int w = tid >> 6, l = tid & 63, l15 = l & 15, lq = l >> 4;
  int fw = fb + 96 * w;
  int loff = l15 * 32 + 8 * lq;
  f32x4 acc[2][6];
  for (int mf = 0; mf < 2; mf++) for (int nf = 0; nf < 6; nf++) acc[mf][nf] = (f32x4){0.f, 0.f, 0.f, 0.f};
  for (int kk = 0; kk < 16; kk++) {
    s16x8 a[2], bbf[6];
    for (int mf = 0; mf < 2; mf++)
      a[mf] = *(const s16x8*)(wfc_t + ((size_t)((cb >> 4) + mf) * CT32 + kk) * 512 + loff);
    for (int nf = 0; nf < 6; nf++)
      bbf[nf] = *(const s16x8*)(px_t + ((size_t)((fw >> 4) + nf) * CT32 + kk) * 512 + loff);
    for (int mf = 0; mf < 2; mf++)
      for (int nf = 0; nf < 6; nf++)
        acc[mf][nf] = __builtin_amdgcn_mfma_f32_16x16x32_bf16(a[mf], bbf[nf], acc[mf][nf], 0, 0, 0);
  }
  float s8[2][4], q8[2][4];
  for (int mf = 0; mf < 2; mf++)
    for (int r = 0; r < 4; r++) {
      int c2 = cb + 16 * mf + 4 * lq + r;
      float bias = bfc[c2];
      float s = 0.f, q = 0.f;
      for (int nf = 0; nf < 6; nf++) {
        float v = acc[mf][nf][r] + bias;
        int flat = fw + 16 * nf + l15;
        int b2 = flat / NN;
        int n = flat - b2 * NN;
        c16[((size_t)b2 * CC + c2) * NN + n] = f2bf(v);
        s += v; q += v * v;
      }
      s8[mf][r] = s; q8[mf][r] = q;
    }
  for (int mf = 0; mf < 2; mf++)
    for (int r = 0; r < 4; r++) {
      float s = s8[mf][r], q = q8[mf][r];
      s += __shfl_xor(s, 1); q += __shfl_xor(q, 1);
      s += __shfl_xor(s, 2); q += __shfl_xor(q, 2);
      s += __shfl_xor(s, 4); q += __shfl_xor(q, 4);
      s += __shfl_xor(s, 8); q += __shfl_xor(q, 8);
      s8[mf][r] = s; q8[mf][r] = q;
    }
  if (l15 == 0)
    for (int mf = 0; mf < 2; mf++)
      for (int r = 0; r < 4; r++) {
        int idx = 16 * mf + 4 * lq + r;
        pss[w][idx] = s8[mf][r];
        psq[w][idx] = q8[mf][r];
      }
  __syncthreads();
  if (tid < 32) {
    float s = pss[0][tid] + pss[1][tid] + pss[2][tid] + pss[3][tid];
    float q = psq[0][tid] + psq[1][tid] + psq[2][tid] + psq[3][tid];
    partials[(size_t)(cb + tid) * NYB + yb] = make_float2(s, q);
  }
}

// ---------------- BN finalize + apply + ReLU (stats reduction fused in) ----------------
__global__ void k_bn(const unsigned short* __restrict__ c16, float* __restrict__ out,
                     const float2* __restrict__ partials, const float* __restrict__ gamma,
                     const float* __restrict__ beta) {
  int idx = blockIdx.x * 256 + threadIdx.x;  // ushort8 index
  const int total = BB * CC * NN / 8;
  if (idx >= total) return;
  int c = (idx / (NN / 8)) & (CC - 1);
  float s = 0.f, q = 0.f;
#pragma unroll
  for (int i = 0; i < NYB; i++) {
    float2 p = partials[(size_t)c * NYB + i];
    s += p.x; q += p.y;
  }
  const float invn = 1.0f / (BB * NN);
  float mean = s * invn;
  float var = q * invn - mean * mean;
  float a = gamma[c] * rsqrtf(var + 1e-5f);
  float b2 = beta[c] - mean * a;
  s16x8 v = ((const s16x8*)c16)[idx];
  f32x4 o0, o1;
  for (int i = 0; i < 4; i++) o0[i] = fmaxf(0.f, bf2f((unsigned short)v[i]) * a + b2);
  for (int i = 0; i < 4; i++) o1[i] = fmaxf(0.f, bf2f((unsigned short)v[4 + i]) * a + b2);
  ((f32x4*)out)[idx * 2] = o0;
  ((f32x4*)out)[idx * 2 + 1] = o1;
}

extern "C" void kernel_launch(void* const* d_in, const int* in_sizes, int n_in,
                              void* d_out, int out_size, void* d_ws, size_t ws_size,
                              hipStream_t stream) {
  const float* x = (const float*)d_in[0];
  const float* Wq = (const float*)d_in[1];
  const float* Wk = (const float*)d_in[2];
  const float* Wv = (const float*)d_in[3];
  const float* align_w = (const float*)d_in[4];
  const float* Wfc = (const float*)d_in[5];
  const float* bfc = (const float*)d_in[6];
  const float* gamma = (const float*)d_in[7];
  const float* beta = (const float*)d_in[8];
  float* out = (float*)d_out;

  char* ws = (char*)d_ws;
  const size_t sz_px = (size_t)BB * NN * CC * 2;  // px_t / content, in-place
  const size_t sz_q = (size_t)BB * NN * 64 * 2;
  const size_t sz_vr = (size_t)BB * NN * CC * 2;
  unsigned short* px_t = (unsigned short*)(ws);
  unsigned short* q_t = (unsigned short*)(ws + sz_px);
  unsigned short* k_t = (unsigned short*)(ws + sz_px + sz_q);
  unsigned short* c16 = (unsigned short*)(ws + sz_px + 2 * sz_q);
  unsigned short* vt_t = (unsigned short*)(ws + sz_px + 2 * sz_q + sz_vr);
  unsigned short* wcat_t = (unsigned short*)(ws + sz_px + 2 * sz_q + 2 * sz_vr);
  unsigned short* wfc_t = (unsigned short*)(ws + sz_px + 2 * sz_q + 2 * sz_vr + 640 * 512 * 2);
  float2* partials = (float2*)(ws + sz_px + 2 * sz_q + 2 * sz_vr + 640 * 512 * 2 + 512 * 512 * 2);

  k_prep_w<<<(640 * 512 + 512 * 512 + 255) / 256, 256, 0, stream>>>(Wq, Wk, Wv, Wfc, wcat_t, wfc_t);
  k_px<<<dim3(BB, NN / 32, 4), 256, 0, stream>>>(x, px_t);
  k_qkv<<<864, 256, 0, stream>>>(px_t, wcat_t, align_w, q_t, k_t, vt_t);
  k_attn<<<768, 256, 0, stream>>>(q_t, k_t, vt_t, px_t);
  k_fc<<<768, 256, 0, stream>>>(px_t, wfc_t, bfc, c16, partials);
  k_bn<<<(BB * CC * NN / 8 + 255) / 256, 256, 0, stream>>>(c16, out, partials, gamma, beta);
}

// Round 12
// 165.996 us; speedup vs baseline: 1.5771x; 1.0409x over previous
//
#include <hip/hip_runtime.h>
#include <stdint.h>

#define BB 8
#define CC 512
#define NN 2304
#define NT16 (NN / 16)  // 144
#define NT32 (NN / 32)  // 72
#define CT32 (CC / 32)  // 16
#define NYB 48          // k_fc y-blocks (stats partials)

typedef float f32x4 __attribute__((ext_vector_type(4)));
typedef short s16x8 __attribute__((ext_vector_type(8)));

__device__ __forceinline__ unsigned short f2bf(float f) {
  union { float f; uint32_t u; } v; v.f = f;
  uint32_t u = v.u;
  return (unsigned short)((u + 0x7FFFu + ((u >> 16) & 1u)) >> 16);
}
__device__ __forceinline__ float bf2f(unsigned short b) {
  union { uint32_t u; float f; } v; v.u = ((uint32_t)b) << 16;
  return v.f;
}
__device__ __forceinline__ uint32_t cvtpk(float lo, float hi) {
  uint32_t r;
  asm("v_cvt_pk_bf16_f32 %0, %1, %2" : "=v"(r) : "v"(lo), "v"(hi));
  return r;
}

// Tiled layout everywhere: buf[row/16][k/32][16][32], 1KB tiles matching the MFMA
// fragment (lane l15 = row, 8*lq = k-offset) -> fragment load = one contiguous
// 1KB wave transaction (R4 win: 217->91us on k_attn).
// k_attn ledger: R6 reorder / R9 occupancy / R10 fewer-barriers all failed to beat
// the R8 config (82.8us) -> k_attn is frozen at that config (structural floor:
// ~26us L2 V-stream + ~22us MFMA + ~26us VALU, imperfect overlap).
// R12: k_prep_w absorbed into k_px (z=4 slice); k_stats2 split back out of k_bn
// (fused version cost 453MB of redundant L2 partial reads).

// ---------------- px_t transpose + weight prep (merged) ----------------
// grid (8, 72, 5): z<4 -> px_t[(b*NN+n)/16][c/32][16][32] = bf16(x[b][c][n]);
// z==4 -> 576 blocks convert [Wq|Wk|Wv] + Wfc to tiled bf16 (4 elems/thread).
__global__ void k_px(const float* __restrict__ x, unsigned short* __restrict__ px_t,
                     const float* __restrict__ Wq, const float* __restrict__ Wk,
                     const float* __restrict__ Wv, const float* __restrict__ Wfc,
                     unsigned short* __restrict__ wcat_t, unsigned short* __restrict__ wfc_t) {
  if (blockIdx.z == 4) {
    const int tot_cat = 640 * 512;
    int blk = blockIdx.x * (NN / 32) + blockIdx.y;  // 0..575
    int base = blk * 1024 + threadIdx.x;
    for (int u = 0; u < 4; u++) {
      int idx = base + u * 256;
      if (idx < tot_cat) {
        int tile = idx >> 9, inner = idx & 511;
        int j = (tile >> 4) * 16 + (inner >> 5);
        int k = (tile & 15) * 32 + (inner & 31);
        float v = (j < 64) ? Wq[j * 512 + k] : ((j < 128) ? Wk[(j - 64) * 512 + k] : Wv[(j - 128) * 512 + k]);
        wcat_t[idx] = f2bf(v);
      } else if (idx < tot_cat + 512 * 512) {
        int i2 = idx - tot_cat;
        int tile = i2 >> 9, inner = i2 & 511;
        int j = (tile >> 4) * 16 + (inner >> 5);
        int k = (tile & 15) * 32 + (inner & 31);
        wfc_t[i2] = f2bf(Wfc[j * 512 + k]);
      }
    }
    return;
  }
  __shared__ float t[32][33];
  int b = blockIdx.x;
  int nb = blockIdx.y * 32;
  int cb = blockIdx.z * 32 + (threadIdx.x >= 0 ? 0 : 0);  // z in 0..3 -> cb0
  int cb0 = blockIdx.z * 128;
  int lane = threadIdx.x & 31;
  int row = threadIdx.x >> 5;  // 0..7
  const float* xb = x + (size_t)b * CC * NN;
  int rbase = (b * NN + nb) >> 4;
  for (int z = 0; z < 4; z++) {
    cb = cb0 + z * 32;
    for (int rr = 0; rr < 4; rr++) {
      int c = cb + row + 8 * rr;
      t[row + 8 * rr][lane] = xb[(size_t)c * NN + nb + lane];
    }
    __syncthreads();
    int ct = cb >> 5;
    for (int rr = 0; rr < 4; rr++) {
      int nl = row + 8 * rr;  // 0..31
      size_t off = ((size_t)(rbase + (nl >> 4)) * CT32 + ct) * 512 + (nl & 15) * 32 + lane;
      px_t[off] = f2bf(t[lane][nl]);
    }
    __syncthreads();
  }
}

// ---------------- QKV GEMM, z=3: z0 -> q_t+k_t (tanh/align), z1,2 -> vt_t DIRECT ----------------
__global__ __launch_bounds__(256, 2) void k_qkv(const unsigned short* __restrict__ px_t,
                                                const unsigned short* __restrict__ wcat_t,
                                                const float* __restrict__ align_w,
                                                unsigned short* __restrict__ q_t,
                                                unsigned short* __restrict__ k_t,
                                                unsigned short* __restrict__ vt_t) {
  int bid = blockIdx.x;
  int b = bid & 7;
  int t = bid >> 3;        // 0..107
  int z = t % 3;
  int nb = (t / 3) * 64;
  int tid = threadIdx.x;
  int w = tid >> 6, l = tid & 63, l15 = l & 15, lq = l >> 4;
  int loff = l15 * 32 + 8 * lq;
  int rA = (b * NN + nb) >> 4;
  int nfmax = (z == 0) ? 2 : 4;
  int rowB0 = (z == 0) ? 2 * w : 8 + (z - 1) * 16 + 4 * w;  // wcat_t row-tile base
  f32x4 acc[4][4];
  for (int mf = 0; mf < 4; mf++) for (int nf = 0; nf < 4; nf++) acc[mf][nf] = (f32x4){0.f, 0.f, 0.f, 0.f};
  for (int kk = 0; kk < 16; kk++) {
    s16x8 a[4], bbf[4];
    for (int mf = 0; mf < 4; mf++)
      a[mf] = *(const s16x8*)(px_t + ((size_t)(rA + mf) * CT32 + kk) * 512 + loff);
    for (int nf = 0; nf < 4; nf++)
      if (nf < nfmax)
        bbf[nf] = *(const s16x8*)(wcat_t + ((size_t)(rowB0 + nf) * CT32 + kk) * 512 + loff);
    for (int mf = 0; mf < 4; mf++)
      for (int nf = 0; nf < 4; nf++)
        if (nf < nfmax)
          acc[mf][nf] = __builtin_amdgcn_mfma_f32_16x16x32_bf16(a[mf], bbf[nf], acc[mf][nf], 0, 0, 0);
  }
  if (z == 0) {
    // j = 32w + 16nf + l15; w<2 -> q (j<64), w>=2 -> k
    for (int mf = 0; mf < 4; mf++)
      for (int nf = 0; nf < 2; nf++)
        for (int r = 0; r < 4; r++) {
          int j = 32 * w + 16 * nf + l15;
          int nl = 4 * lq + r;
          float v = tanhf(acc[mf][nf][r]);
          if (w < 2) {
            v *= align_w[j];
            q_t[((size_t)(rA + mf) * 2 + w) * 512 + nl * 32 + (j & 31)] = f2bf(v);
          } else {
            k_t[((size_t)(rA + mf) * 2 + (w - 2)) * 512 + nl * 32 + (j & 31)] = f2bf(v);
          }
        }
  } else {
    // c = (z-1)*256 + 64w + 16nf + l15 ; n = nb + 16mf + 4lq + r (r=0..3 consecutive)
    unsigned short* vtb = vt_t + (size_t)b * (CC / 16) * NT32 * 512;
    for (int mf = 0; mf < 4; mf++)
      for (int nf = 0; nf < 4; nf++) {
        int c = (z - 1) * 256 + 64 * w + 16 * nf + l15;
        uint2 pp;
        pp.x = cvtpk(acc[mf][nf][0], acc[mf][nf][1]);
        pp.y = cvtpk(acc[mf][nf][2], acc[mf][nf][3]);
        int nlo = 16 * (mf & 1) + 4 * lq;
        size_t off = ((size_t)(c >> 4) * NT32 + (nb >> 5) + (mf >> 1)) * 512 + (c & 15) * 32 + nlo;
        *(uint2*)(vtb + off) = pp;
      }
  }
}

// ---------------- fused attention, i-tile 48, c-split x2 (FROZEN R8 config, 82.8us) ----------------
__global__ __launch_bounds__(256, 3) void k_attn(const unsigned short* __restrict__ q_t,
                                                 const unsigned short* __restrict__ k_t,
                                                 const unsigned short* __restrict__ vt_t,
                                                 unsigned short* __restrict__ px_t /* content in-place */) {
  __shared__ __align__(16) unsigned short e_s[2][48 * 64];
  __shared__ float rs_s[4][48];
  int bid = blockIdx.x;
  int b = bid & 7;           // XCD pin
  int ch = ((bid >> 3) & 1) * 256;
  int ib = (bid >> 4) * 48;
  int tid = threadIdx.x;
  int w = tid >> 6, l = tid & 63, l15 = l & 15, lq = l >> 4;
  int c0 = ch + 64 * w;
  int loff = l15 * 32 + 8 * lq;
  int rQ = (b * NN + ib) >> 4;
  int ktb = b * NT16;
  const unsigned short* vb = vt_t + (size_t)b * (CC / 16) * NT32 * 512;

  s16x8 qa[3][2];
  for (int mf = 0; mf < 3; mf++)
    for (int ks = 0; ks < 2; ks++)
      qa[mf][ks] = *(const s16x8*)(q_t + ((size_t)(rQ + mf) * 2 + ks) * 512 + loff);

  f32x4 acc[3][4];
  for (int mf = 0; mf < 3; mf++) for (int nf = 0; nf < 4; nf++) acc[mf][nf] = (f32x4){0.f, 0.f, 0.f, 0.f};
  float rs[3] = {0.f, 0.f, 0.f};

  s16x8 kf0[2], kf1[2];
  for (int ks = 0; ks < 2; ks++)
    kf0[ks] = *(const s16x8*)(k_t + ((size_t)(ktb + w) * 2 + ks) * 512 + loff);

  auto step = [&](int jt, char* ebuf, s16x8 (&kfu)[2], s16x8 (&kfl)[2]) {
    int jtn = (jt < NN / 64 - 1) ? jt + 1 : jt;
    s16x8 vf[2][4];
    for (int ks = 0; ks < 2; ks++)
      for (int nf = 0; nf < 4; nf++)
        vf[ks][nf] = *(const s16x8*)(vb + ((size_t)((c0 >> 4) + nf) * NT32 + jt * 2 + ks) * 512 + loff);
    for (int ks = 0; ks < 2; ks++)
      kfl[ks] = *(const s16x8*)(k_t + ((size_t)(ktb + jtn * 4 + w) * 2 + ks) * 512 + loff);
    // swapped scores: lane (l15,lq) reg r = S[i = 16mf+l15][j = jb + 16w + 4lq + r]
    f32x4 sc[3];
    for (int mf = 0; mf < 3; mf++) sc[mf] = (f32x4){0.f, 0.f, 0.f, 0.f};
    __builtin_amdgcn_s_setprio(1);
    for (int ks = 0; ks < 2; ks++)
      for (int mf = 0; mf < 3; mf++)
        sc[mf] = __builtin_amdgcn_mfma_f32_16x16x32_bf16(kfu[ks], qa[mf][ks], sc[mf], 0, 0, 0);
    __builtin_amdgcn_s_setprio(0);
    for (int mf = 0; mf < 3; mf++) {
      float e0 = __expf(sc[mf][0]), e1 = __expf(sc[mf][1]);
      float e2 = __expf(sc[mf][2]), e3 = __expf(sc[mf][3]);
      rs[mf] += (e0 + e1) + (e2 + e3);
      uint2 pp;
      pp.x = cvtpk(e0, e1);
      pp.y = cvtpk(e2, e3);
      int i_ = 16 * mf + l15;
      int byte = (i_ * 128 + (16 * w + 4 * lq) * 2) ^ ((i_ & 7) << 4);
      *(uint2*)(ebuf + byte) = pp;
    }
    asm volatile("s_waitcnt lgkmcnt(0)" ::: "memory");
    __builtin_amdgcn_s_barrier();
    __builtin_amdgcn_sched_barrier(0);
    for (int ks = 0; ks < 2; ks++) {
      s16x8 ef[3];
      for (int mf = 0; mf < 3; mf++) {
        int i_ = 16 * mf + l15;
        int byte = (i_ * 128 + 64 * ks + 16 * lq) ^ ((i_ & 7) << 4);
        ef[mf] = *(const s16x8*)((const char*)ebuf + byte);
      }
      __builtin_amdgcn_s_setprio(1);
      for (int nf = 0; nf < 4; nf++)
        for (int mf = 0; mf < 3; mf++)
          acc[mf][nf] = __builtin_amdgcn_mfma_f32_16x16x32_bf16(ef[mf], vf[ks][nf], acc[mf][nf], 0, 0, 0);
      __builtin_amdgcn_s_setprio(0);
    }
  };

  for (int jt = 0; jt < NN / 64; jt += 2) {
    step(jt, (char*)e_s[0], kf0, kf1);
    step(jt + 1, (char*)e_s[1], kf1, kf0);
  }

  // rowsum: lanes sharing l15 (same i) reduce over lq via shfl 16/32, then cross-wave
  for (int mf = 0; mf < 3; mf++) {
    float v = rs[mf];
    v += __shfl_xor(v, 16);
    v += __shfl_xor(v, 32);
    rs[mf] = v;
  }
  if (lq == 0)
    for (int mf = 0; mf < 3; mf++)
      rs_s[w][16 * mf + l15] = rs[mf];
  __syncthreads();
  float inv[3][4];
  for (int mf = 0; mf < 3; mf++)
    for (int r = 0; r < 4; r++) {
      int i = 16 * mf + 4 * lq + r;
      inv[mf][r] = 1.0f / (rs_s[0][i] + rs_s[1][i] + rs_s[2][i] + rs_s[3][i]);
    }
  // content = px + attn@v, in-place RMW on px_t (disjoint per lane/block)
  for (int mf = 0; mf < 3; mf++)
    for (int nf = 0; nf < 4; nf++)
      for (int r = 0; r < 4; r++) {
        int i = 16 * mf + 4 * lq + r;
        int bn = b * NN + ib + i;
        int c = c0 + 16 * nf + l15;
        size_t off = ((size_t)(bn >> 4) * CT32 + (c >> 5)) * 512 + (bn & 15) * 32 + (c & 31);
        px_t[off] = f2bf(bf2f(px_t[off]) + acc[mf][nf][r] * inv[mf][r]);
      }
}

// ---------------- FC + fused BN partial stats; bf16 output c16 ----------------
__global__ __launch_bounds__(256, 3) void k_fc(const unsigned short* __restrict__ px_t,
                                               const unsigned short* __restrict__ wfc_t,
                                               const float* __restrict__ bfc,
                                               unsigned short* __restrict__ c16,
                                               float2* __restrict__ partials) {
  __shared__ float pss[4][32], psq[4][32];
  int bid = blockIdx.x;
  int s_ = bid >> 3;
  int yb = (bid & 7) + 8 * (s_ % 6);
  int cb = (s_ / 6) * 32;
  int fb = yb * 384;
  int tid = threadIdx.x;
  int w = tid >> 6, l = tid & 63, l15 = l & 15, lq = l >> 4;
  int fw = fb + 96 * w;
  int loff = l15 * 32 + 8 * lq;
  f32x4 acc[2][6];
  for (int mf = 0; mf < 2; mf++) for (int nf = 0; nf < 6; nf++) acc[mf][nf] = (f32x4){0.f, 0.f, 0.f, 0.f};
  for (int kk = 0; kk < 16; kk++) {
    s16x8 a[2], bbf[6];
    for (int mf = 0; mf < 2; mf++)
      a[mf] = *(const s16x8*)(wfc_t + ((size_t)((cb >> 4) + mf) * CT32 + kk) * 512 + loff);
    for (int nf = 0; nf < 6; nf++)
      bbf[nf] = *(const s16x8*)(px_t + ((size_t)((fw >> 4) + nf) * CT32 + kk) * 512 + loff);
    for (int mf = 0; mf < 2; mf++)
      for (int nf = 0; nf < 6; nf++)
        acc[mf][nf] = __builtin_amdgcn_mfma_f32_16x16x32_bf16(a[mf], bbf[nf], acc[mf][nf], 0, 0, 0);
  }
  float s8[2][4], q8[2][4];
  for (int mf = 0; mf < 2; mf++)
    for (int r = 0; r < 4; r++) {
      int c2 = cb + 16 * mf + 4 * lq + r;
      float bias = bfc[c2];
      float s = 0.f, q = 0.f;
      for (int nf = 0; nf < 6; nf++) {
        float v = acc[mf][nf][r] + bias;
        int flat = fw + 16 * nf + l15;
        int b2 = flat / NN;
        int n = flat - b2 * NN;
        c16[((size_t)b2 * CC + c2) * NN + n] = f2bf(v);
        s += v; q += v * v;
      }
      s8[mf][r] = s; q8[mf][r] = q;
    }
  for (int mf = 0; mf < 2; mf++)
    for (int r = 0; r < 4; r++) {
      float s = s8[mf][r], q = q8[mf][r];
      s += __shfl_xor(s, 1); q += __shfl_xor(q, 1);
      s += __shfl_xor(s, 2); q += __shfl_xor(q, 2);
      s += __shfl_xor(s, 4); q += __shfl_xor(q, 4);
      s += __shfl_xor(s, 8); q += __shfl_xor(q, 8);
      s8[mf][r] = s; q8[mf][r] = q;
    }
  if (l15 == 0)
    for (int mf = 0; mf < 2; mf++)
      for (int r = 0; r < 4; r++) {
        int idx = 16 * mf + 4 * lq + r;
        pss[w][idx] = s8[mf][r];
        psq[w][idx] = q8[mf][r];
      }
  __syncthreads();
  if (tid < 32) {
    float s = pss[0][tid] + pss[1][tid] + pss[2][tid] + pss[3][tid];
    float q = psq[0][tid] + psq[1][tid] + psq[2][tid] + psq[3][tid];
    partials[(size_t)(cb + tid) * NYB + yb] = make_float2(s, q);
  }
}

// ---------------- BN stats finalize: 512 channels, 48 partials each ----------------
__global__ void k_stats2(const float2* __restrict__ partials, const float* __restrict__ gamma,
                         const float* __restrict__ beta, float2* __restrict__ ab) {
  int c = blockIdx.x * 256 + threadIdx.x;
  if (c >= CC) return;
  float s = 0.f, q = 0.f;
  for (int i = 0; i < NYB; i++) {
    float2 p = partials[(size_t)c * NYB + i];
    s += p.x; q += p.y;
  }
  const float invn = 1.0f / (BB * NN);
  float mean = s * invn;
  float var = q * invn - mean * mean;
  float a = gamma[c] * rsqrtf(var + 1e-5f);
  ab[c] = make_float2(a, beta[c] - mean * a);
}

// ---------------- BN apply + ReLU: read bf16 c16 + ab, write fp32 out ----------------
__global__ void k_bn(const unsigned short* __restrict__ c16, float* __restrict__ out,
                     const float2* __restrict__ ab) {
  int idx = blockIdx.x * 256 + threadIdx.x;  // ushort8 index
  const int total = BB * CC * NN / 8;
  if (idx >= total) return;
  int c = (idx / (NN / 8)) & (CC - 1);
  float2 p = ab[c];
  s16x8 v = ((const s16x8*)c16)[idx];
  f32x4 o0, o1;
  for (int i = 0; i < 4; i++) o0[i] = fmaxf(0.f, bf2f((unsigned short)v[i]) * p.x + p.y);
  for (int i = 0; i < 4; i++) o1[i] = fmaxf(0.f, bf2f((unsigned short)v[4 + i]) * p.x + p.y);
  ((f32x4*)out)[idx * 2] = o0;
  ((f32x4*)out)[idx * 2 + 1] = o1;
}

extern "C" void kernel_launch(void* const* d_in, const int* in_sizes, int n_in,
                              void* d_out, int out_size, void* d_ws, size_t ws_size,
                              hipStream_t stream) {
  const float* x = (const float*)d_in[0];
  const float* Wq = (const float*)d_in[1];
  const float* Wk = (const float*)d_in[2];
  const float* Wv = (const float*)d_in[3];
  const float* align_w = (const float*)d_in[4];
  const float* Wfc = (const float*)d_in[5];
  const float* bfc = (const float*)d_in[6];
  const float* gamma = (const float*)d_in[7];
  const float* beta = (const float*)d_in[8];
  float* out = (float*)d_out;

  char* ws = (char*)d_ws;
  const size_t sz_px = (size_t)BB * NN * CC * 2;  // px_t / content, in-place
  const size_t sz_q = (size_t)BB * NN * 64 * 2;
  const size_t sz_vr = (size_t)BB * NN * CC * 2;
  unsigned short* px_t = (unsigned short*)(ws);
  unsigned short* q_t = (unsigned short*)(ws + sz_px);
  unsigned short* k_t = (unsigned short*)(ws + sz_px + sz_q);
  unsigned short* c16 = (unsigned short*)(ws + sz_px + 2 * sz_q);
  unsigned short* vt_t = (unsigned short*)(ws + sz_px + 2 * sz_q + sz_vr);
  unsigned short* wcat_t = (unsigned short*)(ws + sz_px + 2 * sz_q + 2 * sz_vr);
  unsigned short* wfc_t = (unsigned short*)(ws + sz_px + 2 * sz_q + 2 * sz_vr + 640 * 512 * 2);
  float2* partials = (float2*)(ws + sz_px + 2 * sz_q + 2 * sz_vr + 640 * 512 * 2 + 512 * 512 * 2);
  float2* ab = (float2*)((char*)partials + (size_t)CC * NYB * sizeof(float2));

  k_px<<<dim3(BB, NN / 32, 5), 256, 0, stream>>>(x, px_t, Wq, Wk, Wv, Wfc, wcat_t, wfc_t);
  k_qkv<<<864, 256, 0, stream>>>(px_t, wcat_t, align_w, q_t, k_t, vt_t);
  k_attn<<<768, 256, 0, stream>>>(q_t, k_t, vt_t, px_t);
  k_fc<<<768, 256, 0, stream>>>(px_t, wfc_t, bfc, c16, partials);
  k_stats2<<<2, 256, 0, stream>>>(partials, gamma, beta, ab);
  k_bn<<<(BB * CC * NN / 8 + 255) / 256, 256, 0, stream>>>(c16, out, ab);
}